// Round 14
// baseline (352.418 us; speedup 1.0000x reference)
//
#include <hip/hip_runtime.h>

// ---------------------------------------------------------------------------
// Tensor_CSPNet forward, restructured:
//   out[b,o] = sum_h <G[o,h], log(V_h^T X[b,h] V_h + D_h)> + const[o]
// ReEig stages are provably no-ops (all eigenvalues >= 0.5 >> 1e-4).
// Eigensolve: one-sided Hestenes Jacobi, pair-per-lane in registers,
// 16-lane groups (11 active), DPP circle-method migration.
// R14: ILP surgery — projection o-loop unrolled in pairs (2 independent
// dot-chains in flight; was #pragma unroll 1 since R3's register crunch,
// obsolete at VGPR=64 with grid-capped occupancy), build k-loop unroll 4.
// Sweep config frozen (exits pinned at sweep 3 across eps2 1e-6..1e-4).
// ---------------------------------------------------------------------------

#define WS_CONST 484                     // 4     : fc_w@conv_b + fc_b
#define WS_VT    512                     // 27*484: Vt[h][j][k] = V_h[k][j]
#define WS_V     (512 + 13068)           // 27*528: V[h][k][j], rows padded to 24
#define WS_D     (13580 + 14256)         // 27*484: D_h row-major (sym)
#define WS_G     (27836 + 13068)         // 4*27*528: G[o][h], rows padded to 24
#define G_STRIDE 528
#define V_STRIDE 528

typedef float v2f __attribute__((ext_vector_type(2)));

static __device__ __forceinline__ float dpp_shl1(float x) { // lane m <- lane m+1 (within 16-row)
  return __int_as_float(__builtin_amdgcn_mov_dpp(__float_as_int(x), 0x101, 0xf, 0xf, true));
}
static __device__ __forceinline__ float dpp_shr1(float x) { // lane m <- lane m-1 (within 16-row)
  return __int_as_float(__builtin_amdgcn_mov_dpp(__float_as_int(x), 0x111, 0xf, 0xf, true));
}

// one-sided Jacobi sweeps on column pairs held in registers (16-lane groups,
// lanes 0..10 active). Per-matrix convergence: offF2 = sum over the sweep's
// 231 pair-tests of d^2; exit at sweep s>=minsweep if previous sweep had
// offF2 <= eps2 * sum(lambda_i^2) for ALL 4 matrices in the wave.
static __device__ __forceinline__ void jacobi_sweeps(v2f wl[11], v2f wr[11],
                                                     bool is0, bool is10, bool inert,
                                                     int minsweep, float eps2) {
  int okprev = 0;
  #pragma unroll 1
  for (int sweep = 0; sweep < 5; ++sweep) {
    if (sweep >= minsweep && __all(okprev)) break;
    // fresh norms each sweep
    v2f na = (v2f)(0.f), nb = (v2f)(0.f);
    #pragma unroll
    for (int i = 0; i < 11; ++i) { na += wl[i]*wl[i]; nb += wr[i]*wr[i]; }
    float nL = na.x + na.y, nR = nb.x + nb.y;
    // Q = sum lambda_i^4 over the group's 22 columns (inert lanes gated out)
    float q = inert ? 0.f : (nL*nL + nR*nR);
    q += __shfl_xor(q, 1, 16);
    q += __shfl_xor(q, 2, 16);
    q += __shfl_xor(q, 4, 16);
    q += __shfl_xor(q, 8, 16);
    float dacc = 0.f;
    #pragma unroll 1
    for (int r = 0; r < 21; ++r) {
      v2f da = (v2f)(0.f), db = (v2f)(0.f);
      #pragma unroll
      for (int i = 0; i < 10; i += 2) { da += wl[i]*wr[i]; db += wl[i+1]*wr[i+1]; }
      da += wl[10]*wr[10];
      float d = (da.x + da.y) + (db.x + db.y);
      dacc += d*d;
      // R9 rotation math (measured fastest): tau chain
      float ad  = fabsf(d);
      float tau = (nR - nL)*0.5f*__builtin_amdgcn_rcpf(d);
      float sq  = sqrtf(1.0f + tau*tau);
      float t   = copysignf(__builtin_amdgcn_rcpf(fabsf(tau) + sq), tau);
      float c   = __builtin_amdgcn_rsqf(1.0f + t*t);
      float s   = t*c;
      bool tiny = (ad < 1e-28f);
      c = tiny ? 1.0f : c;
      s = tiny ? 0.0f : s;
      float cc = c*c, ss = s*s, cs2 = 2.0f*c*s;
      float nLn = cc*nL - cs2*d + ss*nR;
      float nRn = ss*nL + cs2*d + cc*nR;
      v2f cv = (v2f)(c), sv = (v2f)(s);
      #pragma unroll
      for (int i = 0; i < 11; ++i) {
        v2f nl = cv*wl[i] - sv*wr[i];
        v2f nr = sv*wl[i] + cv*wr[i];
        float tlx = dpp_shl1(nl.x), tly = dpp_shl1(nl.y);
        float trx = dpp_shr1(nr.x), trY = dpp_shr1(nr.y);
        wl[i].x = is0 ? nl.x : (is10 ? nr.x : tlx);
        wl[i].y = is0 ? nl.y : (is10 ? nr.y : tly);
        wr[i].x = is0 ? tlx : trx;
        wr[i].y = is0 ? tly : trY;
      }
      {
        float tl = dpp_shl1(nLn), tr = dpp_shr1(nRn);
        nL = is0 ? nLn : (is10 ? nRn : tl);
        nR = is0 ? tl : tr;
      }
    }
    float ds = inert ? 0.f : dacc;     // gate junk/NaN AFTER accumulation
    ds += __shfl_xor(ds, 1, 16);
    ds += __shfl_xor(ds, 2, 16);
    ds += __shfl_xor(ds, 4, 16);
    ds += __shfl_xor(ds, 8, 16);
    okprev = (ds <= eps2*q);
  }
}

// ---------------- prep: Jacobi(bn,rm) -> S -> per-h Vt, V, D, G ------------
// LDS layout (floats):
//  [0,484)    w'bn cols (then S)      [484,968)   w'rm cols
//  [968,1452) Gbn = bn^{1/2}          [1452,1936) Grm = rm^{-1/2}
//  [1936,2960) sW1   [2960,3664) sW2  [3664,4368) sU
//  [4368,4588) sE    [4588,6524) sG
__global__ void prep_kernel(const float* __restrict__ rm, const float* __restrict__ bn,
                            const float* __restrict__ W1, const float* __restrict__ W2,
                            const float* __restrict__ conv_w, const float* __restrict__ fc_w,
                            const float* __restrict__ conv_b, const float* __restrict__ fc_b,
                            float* __restrict__ ws, float* __restrict__ out) {
  __shared__ float buf[6524];
  int tid = threadIdx.x, h = blockIdx.x;
  float* sS  = buf;
  float* Gbn = buf + 968;
  float* Grm = buf + 1452;
  float* sW1 = buf + 1936;
  float* sW2 = buf + 2960;
  float* sU  = buf + 3664;
  float* sE  = buf + 4368;
  float* sG  = buf + 4588;

  if (h == 0)  // zero the atomic-add target (replaces memset dispatch)
    for (int idx = tid; idx < 2048; idx += 256) out[idx] = 0.f;

  if (tid < 64) {
    // wave 0: in-register Jacobi on bn (group 0), rm (group 1); 2,3 = bn dup
    const int g = tid >> 4, m = tid & 15;
    const int mm = (m < 10) ? m : 10;
    const bool is0 = (m == 0), is10 = (m == 10);
    const float* src = (g == 1) ? rm : bn;
    v2f wl[11], wr[11];
    const v2f* p2 = (const v2f*)(src + mm*44);   // cols 2mm, 2mm+1 (symmetric)
    #pragma unroll
    for (int i = 0; i < 11; ++i) { wl[i] = p2[i]; wr[i] = p2[11+i]; }
    jacobi_sweeps(wl, wr, is0, is10, (m > 10), 3, 1e-7f);
    if (g < 2 && m < 11) {
      v2f na = (v2f)(0.f), nb = (v2f)(0.f);
      #pragma unroll
      for (int i = 0; i < 11; ++i) { na += wl[i]*wl[i]; nb += wr[i]*wr[i]; }
      float nL = na.x + na.y, nR = nb.x + nb.y;
      // A^{1/2} = sum w w^T nL^{-3/4};  A^{-1/2} = sum w w^T nL^{-5/4}
      float e  = (g == 1) ? -0.625f : -0.375f;   // half-exponent folded into w'
      float cL = exp2f(e*log2f(nL)), cR = exp2f(e*log2f(nR));
      float* dst = buf + g*484;
      #pragma unroll
      for (int i = 0; i < 11; ++i) {
        v2f a = wl[i]*cL, bvv = wr[i]*cR;
        dst[(2*m)*22   + 2*i]   = a.x;
        dst[(2*m)*22   + 2*i+1] = a.y;
        dst[(2*m+1)*22 + 2*i]   = bvv.x;
        dst[(2*m+1)*22 + 2*i+1] = bvv.y;
      }
    }
  } else {
    // waves 1-3: stage W1/W2 and compute raw G (independent of Jacobi)
    int t = tid - 64;
    for (int i = t; i < 1024; i += 192) sW1[i] = W1[h*1024+i];
    for (int i = t; i < 704;  i += 192) sW2[i] = W2[h*704+i];
    int wi = h/9, bi = h%9;
    for (int idx = t; idx < 1936; idx += 192) {
      int o = idx/484, r = idx%484;
      float s = 0.f;
      for (int c = 0; c < 48; ++c) s += fc_w[o*48+c]*conv_w[c*13068 + wi*4356 + bi*484 + r];
      sG[idx] = s;
    }
  }
  __syncthreads();
  // Gbn[i][j] = sum_c w'bn[c][i] w'bn[c][j]; same for Grm
  for (int idx = tid; idx < 968; idx += 256) {
    int p = (idx >= 484) ? 1 : 0, r = idx - p*484;
    int i = r/22, j = r%22;
    const float* wc = buf + p*484;
    float s = 0.f;
    for (int c = 0; c < 22; ++c) s += wc[c*22+i]*wc[c*22+j];
    (p ? Grm : Gbn)[r] = s;
  }
  __syncthreads();
  // S = Grm @ Gbn -> buf[0..484) (w' regions dead); U = W1 @ W2 (32x22)
  {
    float tmp[2];
    int nmy = 0;
    for (int idx = tid; idx < 484; idx += 256) {
      int i = idx/22, j = idx%22;
      float s = 0.f;
      for (int k = 0; k < 22; ++k) s += Grm[i*22+k]*Gbn[k*22+j];
      tmp[nmy++] = s;
    }
    for (int idx = tid; idx < 704; idx += 256) {
      int n = idx/22, j = idx%22;
      float s = 0.f;
      for (int k = 0; k < 32; ++k) s += sW1[n*32+k]*sW2[k*22+j];
      sU[idx] = s;
    }
    __syncthreads();
    nmy = 0;
    for (int idx = tid; idx < 484; idx += 256) sS[idx] = tmp[nmy++];
  }
  __syncthreads();
  // V = U_top @ S: write transposed (Vt, packed) and row-major (stride 24)
  for (int idx = tid; idx < 484; idx += 256) {
    int k = idx/22, j = idx%22;
    float s = 0.f;
    for (int l = 0; l < 22; ++l) s += sU[k*22+l]*sS[l*22+j];
    ws[WS_VT + h*484 + j*22 + k] = s;
    ws[WS_V  + h*V_STRIDE + k*24 + j] = s;
  }
  // E = U_bot @ S (10x22)
  for (int idx = tid; idx < 220; idx += 256) {
    int e = idx/22, j = idx%22;
    float s = 0.f;
    for (int l = 0; l < 22; ++l) s += sU[(22+e)*22+l]*sS[l*22+j];
    sE[idx] = s;
  }
  __syncthreads();
  // D = E^T E (22x22, symmetric)
  for (int idx = tid; idx < 484; idx += 256) {
    int i = idx/22, j = idx%22;
    float s = 0.f;
    for (int e = 0; e < 10; ++e) s += sE[e*22+i]*sE[e*22+j];
    ws[WS_D + h*484 + idx] = s;
  }
  // G symmetrized into padded layout
  for (int idx = tid; idx < 1936; idx += 256) {
    int o = idx/484, r = idx%484, i = r/22, j = r%22;
    float v = 0.5f*(sG[o*484+i*22+j] + sG[o*484+j*22+i]);
    ws[WS_G + (o*27+h)*G_STRIDE + i*24 + j] = v;
  }
  if (h == 0 && tid < 4) {
    float s = 0.f;
    for (int c = 0; c < 48; ++c) s += fc_w[tid*48+c]*conv_b[c];
    ws[WS_CONST + tid] = s + fc_b[tid];
  }
}

// ---------------- main: P4 build + one-sided Jacobi + projection -----------
// h is wave-uniform -> V/D/G base pointers uniform -> scalar loads (SMEM).
// Zero LDS; 64-thread blocks (4 matrices) for even CU balance.
__global__ void __launch_bounds__(64, 3) main_kernel(const float* __restrict__ x,
                                                     const float* __restrict__ ws,
                                                     float* __restrict__ out) {
  const int lane = threadIdx.x;
  const int g = lane >> 4, m = lane & 15;
  const int mm = (m < 10) ? m : 10;          // lanes 11..15 mirror pair 10 (inert)
  const int h  = blockIdx.x % 27;            // wave-uniform
  const int b  = (blockIdx.x/27)*4 + g;
  const int id = b*27 + h;                   // matrix index in x

  // V column pair 2mm, 2mm+1 (rows 2mm,2mm+1 of Vt; 44 contiguous floats)
  v2f vl[11], vrr[11];
  {
    const v2f* vb = (const v2f*)(ws + WS_VT + h*484 + mm*44);
    #pragma unroll
    for (int j = 0; j < 11; ++j) { vl[j] = vb[j]; vrr[j] = vb[11+j]; }
  }
  // init w = D rows 2mm, 2mm+1 (columns of symmetric D)
  v2f wl[11], wr[11];
  {
    const v2f* d2 = (const v2f*)(ws + WS_D + h*484 + mm*44);
    #pragma unroll
    for (int j = 0; j < 11; ++j) { wl[j] = d2[j]; wr[j] = d2[11+j]; }
  }
  // streamed build: for each row k, t_k = <Xrow_k, v>, then w += V[k][:] * t_k
  {
    const v2f* X2 = (const v2f*)(x + (size_t)id * 484);
    const float* Vrow = ws + WS_V + h*V_STRIDE;
    #pragma unroll 4
    for (int k = 0; k < 22; ++k) {
      v2f aL = (v2f)(0.f), aR = (v2f)(0.f);
      #pragma unroll
      for (int c = 0; c < 11; ++c) {
        v2f xv = X2[11*k + c];
        aL += xv*vl[c];
        aR += xv*vrr[c];
      }
      float tLk = aL.x + aL.y, tRk = aR.x + aR.y;
      const v2f* vk = (const v2f*)(Vrow + k*24);
      #pragma unroll
      for (int j = 0; j < 11; ++j) {
        v2f q = vk[j];
        wl[j] += q*tLk;
        wr[j] += q*tRk;
      }
    }
  }

  jacobi_sweeps(wl, wr, (m == 0), (m == 10), (m > 10), 2, 1e-4f);

  // log-eig coefficients: L = sum_j (log lam_j / lam_j^2) w_j w_j^T, lam^2 = ||w||^2
  float nL, nR;
  {
    v2f na = (v2f)(0.f), nb = (v2f)(0.f);
    #pragma unroll
    for (int i = 0; i < 11; ++i) { na += wl[i]*wl[i]; nb += wr[i]*wr[i]; }
    nL = na.x + na.y; nR = nb.x + nb.y;
  }
  const float HALF_LN2 = 0.34657359f;        // 0.5*ln(2)
  float coefL = HALF_LN2*log2f(fmaxf(nL, 1e-8f))*__builtin_amdgcn_rcpf(nL);
  float coefR = HALF_LN2*log2f(fmaxf(nR, 1e-8f))*__builtin_amdgcn_rcpf(nR);

  // projection: out[b,o] += sum_cols coef * (w^T G[o,h] w)
  // o processed in PAIRS: two independent G-row streams + dot-chains in
  // flight per k (was unroll 1 -> serialized; VGPR headroom is free at
  // grid-capped occupancy). Per-o FP math unchanged (bit-identical).
  #pragma unroll 1
  for (int op = 0; op < 2; ++op) {
    const float* G0 = ws + WS_G + ((2*op+0)*27+h)*G_STRIDE;
    const float* G1 = ws + WS_G + ((2*op+1)*27+h)*G_STRIDE;
    float qL0 = 0.f, qR0 = 0.f, qL1 = 0.f, qR1 = 0.f;
    #pragma unroll
    for (int k = 0; k < 22; ++k) {
      const v2f* g20 = (const v2f*)(G0 + k*24);
      const v2f* g21 = (const v2f*)(G1 + k*24);
      v2f sa0 = (v2f)(0.f), ra0 = (v2f)(0.f);
      v2f sa1 = (v2f)(0.f), ra1 = (v2f)(0.f);
      #pragma unroll
      for (int j = 0; j < 11; ++j) {
        v2f q0 = g20[j], q1 = g21[j];
        sa0 += q0*wl[j];
        ra0 += q0*wr[j];
        sa1 += q1*wl[j];
        ra1 += q1*wr[j];
      }
      float wLk = wl[k>>1][k&1], wRk = wr[k>>1][k&1];
      qL0 += wLk*(sa0.x + sa0.y);
      qR0 += wRk*(ra0.x + ra0.y);
      qL1 += wLk*(sa1.x + sa1.y);
      qR1 += wRk*(ra1.x + ra1.y);
    }
    float v0 = (m <= 10) ? (coefL*qL0 + coefR*qR0) : 0.0f;
    float v1 = (m <= 10) ? (coefL*qL1 + coefR*qR1) : 0.0f;
    v0 += __shfl_down(v0, 8, 16);
    v1 += __shfl_down(v1, 8, 16);
    v0 += __shfl_down(v0, 4, 16);
    v1 += __shfl_down(v1, 4, 16);
    v0 += __shfl_down(v0, 2, 16);
    v1 += __shfl_down(v1, 2, 16);
    v0 += __shfl_down(v0, 1, 16);
    v1 += __shfl_down(v1, 1, 16);
    if (m == 0) {
      if (h == 0) { v0 += ws[WS_CONST + 2*op]; v1 += ws[WS_CONST + 2*op + 1]; }
      atomicAdd(out + b*4 + 2*op,     v0);
      atomicAdd(out + b*4 + 2*op + 1, v1);
    }
  }
}

extern "C" void kernel_launch(void* const* d_in, const int* in_sizes, int n_in,
                              void* d_out, int out_size, void* d_ws, size_t ws_size,
                              hipStream_t stream) {
  const float* x   = (const float*)d_in[0];
  const float* W1  = (const float*)d_in[1];
  const float* W2  = (const float*)d_in[2];
  const float* rm  = (const float*)d_in[3];
  const float* bn  = (const float*)d_in[4];
  const float* cw  = (const float*)d_in[5];
  const float* cb  = (const float*)d_in[6];
  const float* fw  = (const float*)d_in[7];
  const float* fb  = (const float*)d_in[8];
  float* out = (float*)d_out;
  float* ws  = (float*)d_ws;

  prep_kernel<<<27, 256, 0, stream>>>(rm, bn, W1, W2, cw, fw, cb, fb, ws, out);
  main_kernel<<<3456, 64, 0, stream>>>(x, ws, out);
}

// Round 15
// 337.331 us; speedup vs baseline: 1.0447x; 1.0447x over previous
//
#include <hip/hip_runtime.h>

// ---------------------------------------------------------------------------
// Tensor_CSPNet forward, restructured:
//   out[b,o] = sum_h <G[o,h], log(V_h^T X[b,h] V_h + D_h)> + const[o]
// ReEig stages are provably no-ops (all eigenvalues >= 0.5 >> 1e-4).
// Eigensolve: one-sided Hestenes Jacobi, pair-per-lane in registers,
// 16-lane groups (11 active), DPP circle-method migration.
// R15: revert to R12/R13 measured-best config (337.5 us). R14's ILP
// surgery (paired o-loop, build unroll 4) regressed 229->242 us: at 3.4
// waves/SIMD the chains were already covered; extra live registers
// (VGPR 64->84) hurt scheduling. Frozen best: tau-chain rotation, eps2
// 1e-4 main / 1e-7 prep, minsweep 2/3, 64-thr blocks, wave-uniform h.
// ---------------------------------------------------------------------------

#define WS_CONST 484                     // 4     : fc_w@conv_b + fc_b
#define WS_VT    512                     // 27*484: Vt[h][j][k] = V_h[k][j]
#define WS_V     (512 + 13068)           // 27*528: V[h][k][j], rows padded to 24
#define WS_D     (13580 + 14256)         // 27*484: D_h row-major (sym)
#define WS_G     (27836 + 13068)         // 4*27*528: G[o][h], rows padded to 24
#define G_STRIDE 528
#define V_STRIDE 528

typedef float v2f __attribute__((ext_vector_type(2)));

static __device__ __forceinline__ float dpp_shl1(float x) { // lane m <- lane m+1 (within 16-row)
  return __int_as_float(__builtin_amdgcn_mov_dpp(__float_as_int(x), 0x101, 0xf, 0xf, true));
}
static __device__ __forceinline__ float dpp_shr1(float x) { // lane m <- lane m-1 (within 16-row)
  return __int_as_float(__builtin_amdgcn_mov_dpp(__float_as_int(x), 0x111, 0xf, 0xf, true));
}

// one-sided Jacobi sweeps on column pairs held in registers (16-lane groups,
// lanes 0..10 active). Per-matrix convergence: offF2 = sum over the sweep's
// 231 pair-tests of d^2; exit at sweep s>=minsweep if previous sweep had
// offF2 <= eps2 * sum(lambda_i^2) for ALL 4 matrices in the wave.
static __device__ __forceinline__ void jacobi_sweeps(v2f wl[11], v2f wr[11],
                                                     bool is0, bool is10, bool inert,
                                                     int minsweep, float eps2) {
  int okprev = 0;
  #pragma unroll 1
  for (int sweep = 0; sweep < 5; ++sweep) {
    if (sweep >= minsweep && __all(okprev)) break;
    // fresh norms each sweep
    v2f na = (v2f)(0.f), nb = (v2f)(0.f);
    #pragma unroll
    for (int i = 0; i < 11; ++i) { na += wl[i]*wl[i]; nb += wr[i]*wr[i]; }
    float nL = na.x + na.y, nR = nb.x + nb.y;
    // Q = sum lambda_i^4 over the group's 22 columns (inert lanes gated out)
    float q = inert ? 0.f : (nL*nL + nR*nR);
    q += __shfl_xor(q, 1, 16);
    q += __shfl_xor(q, 2, 16);
    q += __shfl_xor(q, 4, 16);
    q += __shfl_xor(q, 8, 16);
    float dacc = 0.f;
    #pragma unroll 1
    for (int r = 0; r < 21; ++r) {
      v2f da = (v2f)(0.f), db = (v2f)(0.f);
      #pragma unroll
      for (int i = 0; i < 10; i += 2) { da += wl[i]*wr[i]; db += wl[i+1]*wr[i+1]; }
      da += wl[10]*wr[10];
      float d = (da.x + da.y) + (db.x + db.y);
      dacc += d*d;
      // R9 rotation math (measured fastest): tau chain
      float ad  = fabsf(d);
      float tau = (nR - nL)*0.5f*__builtin_amdgcn_rcpf(d);
      float sq  = sqrtf(1.0f + tau*tau);
      float t   = copysignf(__builtin_amdgcn_rcpf(fabsf(tau) + sq), tau);
      float c   = __builtin_amdgcn_rsqf(1.0f + t*t);
      float s   = t*c;
      bool tiny = (ad < 1e-28f);
      c = tiny ? 1.0f : c;
      s = tiny ? 0.0f : s;
      float cc = c*c, ss = s*s, cs2 = 2.0f*c*s;
      float nLn = cc*nL - cs2*d + ss*nR;
      float nRn = ss*nL + cs2*d + cc*nR;
      v2f cv = (v2f)(c), sv = (v2f)(s);
      #pragma unroll
      for (int i = 0; i < 11; ++i) {
        v2f nl = cv*wl[i] - sv*wr[i];
        v2f nr = sv*wl[i] + cv*wr[i];
        float tlx = dpp_shl1(nl.x), tly = dpp_shl1(nl.y);
        float trx = dpp_shr1(nr.x), trY = dpp_shr1(nr.y);
        wl[i].x = is0 ? nl.x : (is10 ? nr.x : tlx);
        wl[i].y = is0 ? nl.y : (is10 ? nr.y : tly);
        wr[i].x = is0 ? tlx : trx;
        wr[i].y = is0 ? tly : trY;
      }
      {
        float tl = dpp_shl1(nLn), tr = dpp_shr1(nRn);
        nL = is0 ? nLn : (is10 ? nRn : tl);
        nR = is0 ? tl : tr;
      }
    }
    float ds = inert ? 0.f : dacc;     // gate junk/NaN AFTER accumulation
    ds += __shfl_xor(ds, 1, 16);
    ds += __shfl_xor(ds, 2, 16);
    ds += __shfl_xor(ds, 4, 16);
    ds += __shfl_xor(ds, 8, 16);
    okprev = (ds <= eps2*q);
  }
}

// ---------------- prep: Jacobi(bn,rm) -> S -> per-h Vt, V, D, G ------------
// LDS layout (floats):
//  [0,484)    w'bn cols (then S)      [484,968)   w'rm cols
//  [968,1452) Gbn = bn^{1/2}          [1452,1936) Grm = rm^{-1/2}
//  [1936,2960) sW1   [2960,3664) sW2  [3664,4368) sU
//  [4368,4588) sE    [4588,6524) sG
__global__ void prep_kernel(const float* __restrict__ rm, const float* __restrict__ bn,
                            const float* __restrict__ W1, const float* __restrict__ W2,
                            const float* __restrict__ conv_w, const float* __restrict__ fc_w,
                            const float* __restrict__ conv_b, const float* __restrict__ fc_b,
                            float* __restrict__ ws, float* __restrict__ out) {
  __shared__ float buf[6524];
  int tid = threadIdx.x, h = blockIdx.x;
  float* sS  = buf;
  float* Gbn = buf + 968;
  float* Grm = buf + 1452;
  float* sW1 = buf + 1936;
  float* sW2 = buf + 2960;
  float* sU  = buf + 3664;
  float* sE  = buf + 4368;
  float* sG  = buf + 4588;

  if (h == 0)  // zero the atomic-add target (replaces memset dispatch)
    for (int idx = tid; idx < 2048; idx += 256) out[idx] = 0.f;

  if (tid < 64) {
    // wave 0: in-register Jacobi on bn (group 0), rm (group 1); 2,3 = bn dup
    const int g = tid >> 4, m = tid & 15;
    const int mm = (m < 10) ? m : 10;
    const bool is0 = (m == 0), is10 = (m == 10);
    const float* src = (g == 1) ? rm : bn;
    v2f wl[11], wr[11];
    const v2f* p2 = (const v2f*)(src + mm*44);   // cols 2mm, 2mm+1 (symmetric)
    #pragma unroll
    for (int i = 0; i < 11; ++i) { wl[i] = p2[i]; wr[i] = p2[11+i]; }
    jacobi_sweeps(wl, wr, is0, is10, (m > 10), 3, 1e-7f);
    if (g < 2 && m < 11) {
      v2f na = (v2f)(0.f), nb = (v2f)(0.f);
      #pragma unroll
      for (int i = 0; i < 11; ++i) { na += wl[i]*wl[i]; nb += wr[i]*wr[i]; }
      float nL = na.x + na.y, nR = nb.x + nb.y;
      // A^{1/2} = sum w w^T nL^{-3/4};  A^{-1/2} = sum w w^T nL^{-5/4}
      float e  = (g == 1) ? -0.625f : -0.375f;   // half-exponent folded into w'
      float cL = exp2f(e*log2f(nL)), cR = exp2f(e*log2f(nR));
      float* dst = buf + g*484;
      #pragma unroll
      for (int i = 0; i < 11; ++i) {
        v2f a = wl[i]*cL, bvv = wr[i]*cR;
        dst[(2*m)*22   + 2*i]   = a.x;
        dst[(2*m)*22   + 2*i+1] = a.y;
        dst[(2*m+1)*22 + 2*i]   = bvv.x;
        dst[(2*m+1)*22 + 2*i+1] = bvv.y;
      }
    }
  } else {
    // waves 1-3: stage W1/W2 and compute raw G (independent of Jacobi)
    int t = tid - 64;
    for (int i = t; i < 1024; i += 192) sW1[i] = W1[h*1024+i];
    for (int i = t; i < 704;  i += 192) sW2[i] = W2[h*704+i];
    int wi = h/9, bi = h%9;
    for (int idx = t; idx < 1936; idx += 192) {
      int o = idx/484, r = idx%484;
      float s = 0.f;
      for (int c = 0; c < 48; ++c) s += fc_w[o*48+c]*conv_w[c*13068 + wi*4356 + bi*484 + r];
      sG[idx] = s;
    }
  }
  __syncthreads();
  // Gbn[i][j] = sum_c w'bn[c][i] w'bn[c][j]; same for Grm
  for (int idx = tid; idx < 968; idx += 256) {
    int p = (idx >= 484) ? 1 : 0, r = idx - p*484;
    int i = r/22, j = r%22;
    const float* wc = buf + p*484;
    float s = 0.f;
    for (int c = 0; c < 22; ++c) s += wc[c*22+i]*wc[c*22+j];
    (p ? Grm : Gbn)[r] = s;
  }
  __syncthreads();
  // S = Grm @ Gbn -> buf[0..484) (w' regions dead); U = W1 @ W2 (32x22)
  {
    float tmp[2];
    int nmy = 0;
    for (int idx = tid; idx < 484; idx += 256) {
      int i = idx/22, j = idx%22;
      float s = 0.f;
      for (int k = 0; k < 22; ++k) s += Grm[i*22+k]*Gbn[k*22+j];
      tmp[nmy++] = s;
    }
    for (int idx = tid; idx < 704; idx += 256) {
      int n = idx/22, j = idx%22;
      float s = 0.f;
      for (int k = 0; k < 32; ++k) s += sW1[n*32+k]*sW2[k*22+j];
      sU[idx] = s;
    }
    __syncthreads();
    nmy = 0;
    for (int idx = tid; idx < 484; idx += 256) sS[idx] = tmp[nmy++];
  }
  __syncthreads();
  // V = U_top @ S: write transposed (Vt, packed) and row-major (stride 24)
  for (int idx = tid; idx < 484; idx += 256) {
    int k = idx/22, j = idx%22;
    float s = 0.f;
    for (int l = 0; l < 22; ++l) s += sU[k*22+l]*sS[l*22+j];
    ws[WS_VT + h*484 + j*22 + k] = s;
    ws[WS_V  + h*V_STRIDE + k*24 + j] = s;
  }
  // E = U_bot @ S (10x22)
  for (int idx = tid; idx < 220; idx += 256) {
    int e = idx/22, j = idx%22;
    float s = 0.f;
    for (int l = 0; l < 22; ++l) s += sU[(22+e)*22+l]*sS[l*22+j];
    sE[idx] = s;
  }
  __syncthreads();
  // D = E^T E (22x22, symmetric)
  for (int idx = tid; idx < 484; idx += 256) {
    int i = idx/22, j = idx%22;
    float s = 0.f;
    for (int e = 0; e < 10; ++e) s += sE[e*22+i]*sE[e*22+j];
    ws[WS_D + h*484 + idx] = s;
  }
  // G symmetrized into padded layout
  for (int idx = tid; idx < 1936; idx += 256) {
    int o = idx/484, r = idx%484, i = r/22, j = r%22;
    float v = 0.5f*(sG[o*484+i*22+j] + sG[o*484+j*22+i]);
    ws[WS_G + (o*27+h)*G_STRIDE + i*24 + j] = v;
  }
  if (h == 0 && tid < 4) {
    float s = 0.f;
    for (int c = 0; c < 48; ++c) s += fc_w[tid*48+c]*conv_b[c];
    ws[WS_CONST + tid] = s + fc_b[tid];
  }
}

// ---------------- main: P4 build + one-sided Jacobi + projection -----------
// h is wave-uniform -> V/D/G base pointers uniform -> scalar loads (SMEM).
// Zero LDS; 64-thread blocks (4 matrices) for even CU balance.
__global__ void __launch_bounds__(64, 3) main_kernel(const float* __restrict__ x,
                                                     const float* __restrict__ ws,
                                                     float* __restrict__ out) {
  const int lane = threadIdx.x;
  const int g = lane >> 4, m = lane & 15;
  const int mm = (m < 10) ? m : 10;          // lanes 11..15 mirror pair 10 (inert)
  const int h  = blockIdx.x % 27;            // wave-uniform
  const int b  = (blockIdx.x/27)*4 + g;
  const int id = b*27 + h;                   // matrix index in x

  // V column pair 2mm, 2mm+1 (rows 2mm,2mm+1 of Vt; 44 contiguous floats)
  v2f vl[11], vrr[11];
  {
    const v2f* vb = (const v2f*)(ws + WS_VT + h*484 + mm*44);
    #pragma unroll
    for (int j = 0; j < 11; ++j) { vl[j] = vb[j]; vrr[j] = vb[11+j]; }
  }
  // init w = D rows 2mm, 2mm+1 (columns of symmetric D)
  v2f wl[11], wr[11];
  {
    const v2f* d2 = (const v2f*)(ws + WS_D + h*484 + mm*44);
    #pragma unroll
    for (int j = 0; j < 11; ++j) { wl[j] = d2[j]; wr[j] = d2[11+j]; }
  }
  // streamed build: for each row k, t_k = <Xrow_k, v>, then w += V[k][:] * t_k
  {
    const v2f* X2 = (const v2f*)(x + (size_t)id * 484);
    const float* Vrow = ws + WS_V + h*V_STRIDE;
    #pragma unroll 2
    for (int k = 0; k < 22; ++k) {
      v2f aL = (v2f)(0.f), aR = (v2f)(0.f);
      #pragma unroll
      for (int c = 0; c < 11; ++c) {
        v2f xv = X2[11*k + c];
        aL += xv*vl[c];
        aR += xv*vrr[c];
      }
      float tLk = aL.x + aL.y, tRk = aR.x + aR.y;
      const v2f* vk = (const v2f*)(Vrow + k*24);
      #pragma unroll
      for (int j = 0; j < 11; ++j) {
        v2f q = vk[j];
        wl[j] += q*tLk;
        wr[j] += q*tRk;
      }
    }
  }

  jacobi_sweeps(wl, wr, (m == 0), (m == 10), (m > 10), 2, 1e-4f);

  // log-eig coefficients: L = sum_j (log lam_j / lam_j^2) w_j w_j^T, lam^2 = ||w||^2
  float nL, nR;
  {
    v2f na = (v2f)(0.f), nb = (v2f)(0.f);
    #pragma unroll
    for (int i = 0; i < 11; ++i) { na += wl[i]*wl[i]; nb += wr[i]*wr[i]; }
    nL = na.x + na.y; nR = nb.x + nb.y;
  }
  const float HALF_LN2 = 0.34657359f;        // 0.5*ln(2)
  float coefL = HALF_LN2*log2f(fmaxf(nL, 1e-8f))*__builtin_amdgcn_rcpf(nL);
  float coefR = HALF_LN2*log2f(fmaxf(nR, 1e-8f))*__builtin_amdgcn_rcpf(nR);

  // projection: out[b,o] += sum_cols coef * (w^T G[o,h] w)
  #pragma unroll 1
  for (int o = 0; o < 4; ++o) {
    const float* Gptr = ws + WS_G + (o*27+h)*G_STRIDE;
    float qL = 0.f, qR = 0.f;
    #pragma unroll
    for (int k = 0; k < 22; ++k) {
      const v2f* g2 = (const v2f*)(Gptr + k*24);
      v2f sa = (v2f)(0.f), ra = (v2f)(0.f);
      #pragma unroll
      for (int j = 0; j < 11; ++j) {
        v2f q = g2[j];
        sa += q*wl[j];
        ra += q*wr[j];
      }
      float wLk = wl[k>>1][k&1], wRk = wr[k>>1][k&1];
      qL += wLk*(sa.x + sa.y);
      qR += wRk*(ra.x + ra.y);
    }
    float v = (m <= 10) ? (coefL*qL + coefR*qR) : 0.0f;
    v += __shfl_down(v, 8, 16);
    v += __shfl_down(v, 4, 16);
    v += __shfl_down(v, 2, 16);
    v += __shfl_down(v, 1, 16);
    if (m == 0) {
      if (h == 0) v += ws[WS_CONST + o];
      atomicAdd(out + b*4 + o, v);
    }
  }
}

extern "C" void kernel_launch(void* const* d_in, const int* in_sizes, int n_in,
                              void* d_out, int out_size, void* d_ws, size_t ws_size,
                              hipStream_t stream) {
  const float* x   = (const float*)d_in[0];
  const float* W1  = (const float*)d_in[1];
  const float* W2  = (const float*)d_in[2];
  const float* rm  = (const float*)d_in[3];
  const float* bn  = (const float*)d_in[4];
  const float* cw  = (const float*)d_in[5];
  const float* cb  = (const float*)d_in[6];
  const float* fw  = (const float*)d_in[7];
  const float* fb  = (const float*)d_in[8];
  float* out = (float*)d_out;
  float* ws  = (float*)d_ws;

  prep_kernel<<<27, 256, 0, stream>>>(rm, bn, W1, W2, cw, fw, cb, fb, ws, out);
  main_kernel<<<3456, 64, 0, stream>>>(x, ws, out);
}